// Round 1
// baseline (1131.784 us; speedup 1.0000x reference)
//
#include <hip/hip_runtime.h>
#include <math.h>

#define B_ROWS 2048
#define P_ROWS 100000
#define D_DIM  128
#define EPSF   1e-6f
#define NP     16          // number of P-chunks (grid.x)
#define BM     64
#define BN     64
#define LDW    132         // padded LDS leading dim (floats); 132*4B rows stay 16B-aligned
#define NT_P   ((P_ROWS + BN - 1) / BN)   // 1563 tiles along P

// ---------------------------------------------------------------------------
// Kernel 1: inverse norms for pool (P rows) and sess (B rows).
// fenmu = sqrt(sum(x*x + EPS)) = sqrt(sum(x*x) + D*EPS)
// ---------------------------------------------------------------------------
__global__ void norms_kernel(const float* __restrict__ sess,
                             const float* __restrict__ pool,
                             float* __restrict__ inv_sess,
                             float* __restrict__ inv_pool) {
    int row  = blockIdx.x * 4 + (threadIdx.x >> 6);   // one wave per row
    int lane = threadIdx.x & 63;
    if (row >= P_ROWS + B_ROWS) return;
    const float* src;
    float* dst;
    if (row < P_ROWS) { src = pool + (size_t)row * D_DIM;            dst = inv_pool + row; }
    else              { src = sess + (size_t)(row - P_ROWS) * D_DIM; dst = inv_sess + (row - P_ROWS); }
    float2 v = ((const float2*)src)[lane];            // 128 floats = 64 lanes x float2
    float s = v.x * v.x + v.y * v.y;
    #pragma unroll
    for (int o = 32; o > 0; o >>= 1) s += __shfl_xor(s, o);
    if (lane == 0) *dst = 1.0f / sqrtf(s + (float)D_DIM * EPSF);
}

// top-3 insert with jax.lax.top_k tie-break (lower index first on equal value)
__device__ __forceinline__ void ins3(float v, int c,
                                     float& v0, int& i0,
                                     float& v1, int& i1,
                                     float& v2, int& i2) {
    bool b0 = (v > v0) || (v == v0 && c < i0);
    bool b1 = (v > v1) || (v == v1 && c < i1);
    bool b2 = (v > v2) || (v == v2 && c < i2);
    if (b0)      { v2 = v1; i2 = i1; v1 = v0; i1 = i0; v0 = v; i0 = c; }
    else if (b1) { v2 = v1; i2 = i1; v1 = v;  i1 = c; }
    else if (b2) { v2 = v;  i2 = c; }
}

// ---------------------------------------------------------------------------
// Kernel 2: fused cosine-GEMM + softmax-denominator + top-3, per P-chunk.
// Grid: (NP, B_ROWS/BM). Block: 256 threads, 64x64 tile, 4x4 micro-tile.
// Thread (tx,ty): rows {ty+16i}, cols {tx+16j}  (stride-16 -> conflict-free LDS)
// Partials out: per (row, chunk): {z, v0, i0, v1, i1, v2, i2, pad} (8 floats)
// ---------------------------------------------------------------------------
__launch_bounds__(256, 2)
__global__ void gemm_topk_kernel(const float* __restrict__ sess,
                                 const float* __restrict__ pool,
                                 const float* __restrict__ inv_sess,
                                 const float* __restrict__ inv_pool,
                                 float* __restrict__ partials) {
    __shared__ float Asm[BM * LDW];
    __shared__ float Bsm[BN * LDW];

    const int tid   = threadIdx.x;
    const int tx    = tid & 15;
    const int ty    = tid >> 4;
    const int chunk = blockIdx.x;
    const int row0  = blockIdx.y * BM;

    // ---- stage A (sess tile) once, pre-scaled by inv_sess ----
    #pragma unroll
    for (int l = 0; l < 8; ++l) {
        int flat = tid + 256 * l;           // 0..2047
        int r    = flat >> 5;               // 0..63
        int k4   = flat & 31;               // 0..31 (float4 index)
        float4 a = ((const float4*)(sess + (size_t)(row0 + r) * D_DIM))[k4];
        float  sc = inv_sess[row0 + r];
        a.x *= sc; a.y *= sc; a.z *= sc; a.w *= sc;
        ((float4*)(Asm + r * LDW))[k4] = a;
    }

    // per-thread running stats for 4 rows
    float z[4]     = {0.f, 0.f, 0.f, 0.f};
    float tv[4][3];
    int   ti[4][3];
    #pragma unroll
    for (int i = 0; i < 4; ++i) {
        tv[i][0] = tv[i][1] = tv[i][2] = -1e30f;
        ti[i][0] = ti[i][1] = ti[i][2] = -1;
    }

    for (int t = chunk; t < NT_P; t += NP) {
        const int p0 = t * BN;
        __syncthreads();                    // prev-iter Bsm reads done (also A-ready gate)
        // ---- stage B (pool tile), pre-scaled by inv_pool; pad OOB rows w/ 0 ----
        #pragma unroll
        for (int l = 0; l < 8; ++l) {
            int flat = tid + 256 * l;
            int r    = flat >> 5;
            int k4   = flat & 31;
            int p    = p0 + r;
            float4 b = make_float4(0.f, 0.f, 0.f, 0.f);
            if (p < P_ROWS) {
                b = ((const float4*)(pool + (size_t)p * D_DIM))[k4];
                float sc = inv_pool[p];
                b.x *= sc; b.y *= sc; b.z *= sc; b.w *= sc;
            }
            ((float4*)(Bsm + r * LDW))[k4] = b;
        }
        __syncthreads();

        // ---- 64x64x128 register-tiled FMA ----
        float acc[4][4] = {};
        #pragma unroll 4
        for (int k4 = 0; k4 < 32; ++k4) {
            float4 a[4], b[4];
            #pragma unroll
            for (int i = 0; i < 4; ++i)
                a[i] = ((const float4*)(Asm + (ty + 16 * i) * LDW))[k4];
            #pragma unroll
            for (int j = 0; j < 4; ++j)
                b[j] = ((const float4*)(Bsm + (tx + 16 * j) * LDW))[k4];
            #pragma unroll
            for (int i = 0; i < 4; ++i)
                #pragma unroll
                for (int j = 0; j < 4; ++j) {
                    acc[i][j] = fmaf(a[i].x, b[j].x, acc[i][j]);
                    acc[i][j] = fmaf(a[i].y, b[j].y, acc[i][j]);
                    acc[i][j] = fmaf(a[i].z, b[j].z, acc[i][j]);
                    acc[i][j] = fmaf(a[i].w, b[j].w, acc[i][j]);
                }
        }

        // ---- epilogue: fold 16 cosines into running (z, top3) ----
        #pragma unroll
        for (int j = 0; j < 4; ++j) {
            int col = p0 + tx + 16 * j;
            if (col < P_ROWS) {
                #pragma unroll
                for (int i = 0; i < 4; ++i) {
                    float v = acc[i][j];
                    z[i] += __expf(v);      // s in [-1,1]: no max-rescale needed
                    // in-thread cols strictly increase -> strict > keeps low idx first
                    if (v > tv[i][0]) {
                        tv[i][2] = tv[i][1]; ti[i][2] = ti[i][1];
                        tv[i][1] = tv[i][0]; ti[i][1] = ti[i][0];
                        tv[i][0] = v;        ti[i][0] = col;
                    } else if (v > tv[i][1]) {
                        tv[i][2] = tv[i][1]; ti[i][2] = ti[i][1];
                        tv[i][1] = v;        ti[i][1] = col;
                    } else if (v > tv[i][2]) {
                        tv[i][2] = v;        ti[i][2] = col;
                    }
                }
            }
        }
    }

    // ---- block-level merge: 16 tx-partials per row ----
    __syncthreads();
    float* red = Asm;                       // reuse: 64*16*7 = 7168 floats <= 8448
    #pragma unroll
    for (int i = 0; i < 4; ++i) {
        int rl = ty + 16 * i;
        float* q = red + (rl * 16 + tx) * 7;
        q[0] = z[i];
        q[1] = tv[i][0]; q[2] = __int_as_float(ti[i][0]);
        q[3] = tv[i][1]; q[4] = __int_as_float(ti[i][1]);
        q[5] = tv[i][2]; q[6] = __int_as_float(ti[i][2]);
    }
    __syncthreads();
    if (tid < 64) {
        float zt = 0.f;
        float v0 = -1e30f, v1 = -1e30f, v2 = -1e30f;
        int   i0 = -1, i1 = -1, i2 = -1;
        for (int txx = 0; txx < 16; ++txx) {
            const float* q = red + (tid * 16 + txx) * 7;
            zt += q[0];
            ins3(q[1], __float_as_int(q[2]), v0, i0, v1, i1, v2, i2);
            ins3(q[3], __float_as_int(q[4]), v0, i0, v1, i1, v2, i2);
            ins3(q[5], __float_as_int(q[6]), v0, i0, v1, i1, v2, i2);
        }
        float* o = partials + ((size_t)(row0 + tid) * NP + chunk) * 8;
        o[0] = zt;
        o[1] = v0; o[2] = __int_as_float(i0);
        o[3] = v1; o[4] = __int_as_float(i1);
        o[5] = v2; o[6] = __int_as_float(i2);
        o[7] = 0.f;
    }
}

// ---------------------------------------------------------------------------
// Kernel 3: merge NP chunk-partials per row, double softmax, gather, write.
// One wave per row; all lanes redundantly merge (broadcast loads), then
// cooperatively gather 3 pool rows + weighted sum.
// ---------------------------------------------------------------------------
__global__ void finalize_kernel(const float* __restrict__ pool,
                                const float* __restrict__ partials,
                                float* __restrict__ out_neighbor,   // [B,128]
                                float* __restrict__ out_costopk,    // [B,3]
                                float* __restrict__ out_sesstopk) { // [B,3,128]
    int row  = blockIdx.x * 4 + (threadIdx.x >> 6);
    int lane = threadIdx.x & 63;
    if (row >= B_ROWS) return;

    float zt = 0.f;
    float v0 = -1e30f, v1 = -1e30f, v2 = -1e30f;
    int   i0 = -1, i1 = -1, i2 = -1;
    for (int c = 0; c < NP; ++c) {
        const float* q = partials + ((size_t)row * NP + c) * 8;
        zt += q[0];
        ins3(q[1], __float_as_int(q[2]), v0, i0, v1, i1, v2, i2);
        ins3(q[3], __float_as_int(q[4]), v0, i0, v1, i1, v2, i2);
        ins3(q[5], __float_as_int(q[6]), v0, i0, v1, i1, v2, i2);
    }

    // first softmax (over all P), evaluated only at the top-3:
    float c0 = __expf(v0) / zt;
    float c1 = __expf(v1) / zt;
    float c2 = __expf(v2) / zt;
    // second softmax over {c0,c1,c2}; c0 is the max since v0>=v1>=v2
    float e1 = __expf(c1 - c0), e2 = __expf(c2 - c0);
    float inv = 1.0f / (1.0f + e1 + e2);
    float w0 = inv, w1 = e1 * inv, w2 = e2 * inv;

    const float2* p0r = (const float2*)(pool + (size_t)i0 * D_DIM);
    const float2* p1r = (const float2*)(pool + (size_t)i1 * D_DIM);
    const float2* p2r = (const float2*)(pool + (size_t)i2 * D_DIM);
    float2 g0 = p0r[lane], g1 = p1r[lane], g2 = p2r[lane];

    float2 nb;
    nb.x = w0 * g0.x + w1 * g1.x + w2 * g2.x;
    nb.y = w0 * g0.y + w1 * g1.y + w2 * g2.y;

    ((float2*)(out_sesstopk + ((size_t)row * 3 + 0) * D_DIM))[lane] = g0;
    ((float2*)(out_sesstopk + ((size_t)row * 3 + 1) * D_DIM))[lane] = g1;
    ((float2*)(out_sesstopk + ((size_t)row * 3 + 2) * D_DIM))[lane] = g2;
    ((float2*)(out_neighbor + (size_t)row * D_DIM))[lane] = nb;
    if (lane == 0) {
        out_costopk[row * 3 + 0] = w0;
        out_costopk[row * 3 + 1] = w1;
        out_costopk[row * 3 + 2] = w2;
    }
}

// ---------------------------------------------------------------------------
extern "C" void kernel_launch(void* const* d_in, const int* in_sizes, int n_in,
                              void* d_out, int out_size, void* d_ws, size_t ws_size,
                              hipStream_t stream) {
    const float* sess = (const float*)d_in[0];   // [2048,128]
    const float* pool = (const float*)d_in[1];   // [100000,128]
    float* out = (float*)d_out;
    float* out_neighbor = out;                              // 2048*128
    float* out_costopk  = out + (size_t)B_ROWS * D_DIM;     // 2048*3
    float* out_sesstopk = out_costopk + (size_t)B_ROWS * 3; // 2048*3*128

    float* inv_pool = (float*)d_ws;                  // P floats
    float* inv_sess = inv_pool + P_ROWS;             // B floats
    float* partials = inv_sess + B_ROWS;             // B*NP*8 floats (~1 MB)

    norms_kernel<<<(P_ROWS + B_ROWS + 3) / 4, 256, 0, stream>>>(
        sess, pool, inv_sess, inv_pool);

    dim3 g2(NP, B_ROWS / BM);
    gemm_topk_kernel<<<g2, 256, 0, stream>>>(
        sess, pool, inv_sess, inv_pool, partials);

    finalize_kernel<<<B_ROWS / 4, 256, 0, stream>>>(
        pool, partials, out_neighbor, out_costopk, out_sesstopk);
}

// Round 3
// 448.596 us; speedup vs baseline: 2.5229x; 2.5229x over previous
//
#include <hip/hip_runtime.h>
#include <math.h>

#define B_ROWS 2048
#define P_ROWS 100000
#define D_DIM  128
#define EPSF   1e-6f
#define NPC    32                 // pool chunks (grid.x of gemm)
#define NT     782                // ceil(100000/128) pool tiles
#define TILE_BYTES 65536          // 128 cols x 256 bf16 (512 B/row)
#define NCAND  (NPC * 3)          // 96 screened candidates per row

typedef short short8 __attribute__((ext_vector_type(8)));
typedef float f32x4  __attribute__((ext_vector_type(4)));

// ---------------------------------------------------------------------------
// bf16 helpers (RNE)
// ---------------------------------------------------------------------------
__device__ __forceinline__ unsigned short f2bf(float f) {
    unsigned u = __float_as_uint(f);
    u += 0x7fffu + ((u >> 16) & 1u);
    return (unsigned short)(u >> 16);
}
__device__ __forceinline__ float bf2f(unsigned short h) {
    return __uint_as_float(((unsigned)h) << 16);
}

// ---------------------------------------------------------------------------
// Kernel 1: inverse norms.  fenmu = sqrt(sum(x*x) + D*EPS)
// ---------------------------------------------------------------------------
__global__ void norms_kernel(const float* __restrict__ sess,
                             const float* __restrict__ pool,
                             float* __restrict__ inv_sess,
                             float* __restrict__ inv_pool) {
    int row  = blockIdx.x * 4 + (threadIdx.x >> 6);
    int lane = threadIdx.x & 63;
    if (row >= P_ROWS + B_ROWS) return;
    const float* src;
    float* dst;
    if (row < P_ROWS) { src = pool + (size_t)row * D_DIM;            dst = inv_pool + row; }
    else              { src = sess + (size_t)(row - P_ROWS) * D_DIM; dst = inv_sess + (row - P_ROWS); }
    float2 v = ((const float2*)src)[lane];
    float s = v.x * v.x + v.y * v.y;
    #pragma unroll
    for (int o = 32; o > 0; o >>= 1) s += __shfl_xor(s, o);
    if (lane == 0) *dst = 1.0f / sqrtf(s + (float)D_DIM * EPSF);
}

// ---------------------------------------------------------------------------
// Kernel 2a: pack sess -> sess2[m][slot 0..31][16B], row-major, no swizzle.
// slot s<16: hi of elements s*8..s*8+7 ; slot s>=16: lo of (s-16)*8..
// ---------------------------------------------------------------------------
__global__ void pack_sess_kernel(const float* __restrict__ sess,
                                 const float* __restrict__ inv_sess,
                                 char* __restrict__ sess2) {
    int item = blockIdx.x * 256 + threadIdx.x;   // 0..32767
    int m = item >> 4, g = item & 15;
    float inv = inv_sess[m];
    const float* src = sess + (size_t)m * D_DIM + g * 8;
    short8 hv, lv;
    #pragma unroll
    for (int j = 0; j < 8; ++j) {
        float w = src[j] * inv;
        unsigned short h = f2bf(w);
        hv[j] = (short)h;
        lv[j] = (short)f2bf(w - bf2f(h));
    }
    char* base = sess2 + (size_t)m * 512;
    *(short8*)(base + g * 16)        = hv;
    *(short8*)(base + (16 + g) * 16) = lv;
}

// ---------------------------------------------------------------------------
// Kernel 2b: pack pool -> pool2[T][c 0..127][slot 0..31][16B], XOR-swizzled:
// stored slot sl holds logical group sg = sl ^ (c&7).  OOB rows -> zeros.
// ---------------------------------------------------------------------------
__global__ void pack_pool_kernel(const float* __restrict__ pool,
                                 const float* __restrict__ inv_pool,
                                 char* __restrict__ pool2) {
    int T = blockIdx.x;
    for (int it = 0; it < 8; ++it) {
        int item = it * 256 + threadIdx.x;   // 0..2047
        int c = item >> 4, g = item & 15;
        int n = T * 128 + c;
        short8 hv = {0,0,0,0,0,0,0,0}, lv = {0,0,0,0,0,0,0,0};
        if (n < P_ROWS) {
            float inv = inv_pool[n];
            const float* src = pool + (size_t)n * D_DIM + g * 8;
            #pragma unroll
            for (int j = 0; j < 8; ++j) {
                float w = src[j] * inv;
                unsigned short h = f2bf(w);
                hv[j] = (short)h;
                lv[j] = (short)f2bf(w - bf2f(h));
            }
        }
        char* base = pool2 + (size_t)T * TILE_BYTES + c * 512;
        int x = c & 7;
        *(short8*)(base + (g ^ x) * 16)          = hv;
        *(short8*)(base + ((16 + g) ^ x) * 16)   = lv;
    }
}

// top-3 insert, fp32 (screen) — lower index wins ties
__device__ __forceinline__ void ins3(float v, int c,
                                     float& v0, int& i0,
                                     float& v1, int& i1,
                                     float& v2, int& i2) {
    bool b0 = (v > v0) || (v == v0 && c < i0);
    bool b1 = (v > v1) || (v == v1 && c < i1);
    bool b2 = (v > v2) || (v == v2 && c < i2);
    if (b0)      { v2 = v1; i2 = i1; v1 = v0; i1 = i0; v0 = v; i0 = c; }
    else if (b1) { v2 = v1; i2 = i1; v1 = v;  i1 = c; }
    else if (b2) { v2 = v;  i2 = c; }
}

// top-3 insert, fp64 (exact rescore) — lower index wins ties
__device__ __forceinline__ void ins3d(double v, int c,
                                      double& v0, int& i0,
                                      double& v1, int& i1,
                                      double& v2, int& i2) {
    bool b0 = (v > v0) || (v == v0 && c < i0);
    bool b1 = (v > v1) || (v == v1 && c < i1);
    bool b2 = (v > v2) || (v == v2 && c < i2);
    if (b0)      { v2 = v1; i2 = i1; v1 = v0; i1 = i0; v0 = v; i0 = c; }
    else if (b1) { v2 = v1; i2 = i1; v1 = v;  i1 = c; }
    else if (b2) { v2 = v;  i2 = c; }
}

__device__ __forceinline__ void async16(const char* g, char* l) {
    __builtin_amdgcn_global_load_lds(
        (const __attribute__((address_space(1))) unsigned int*)g,
        (__attribute__((address_space(3))) unsigned int*)l,
        16, 0, 0);
}

// ---------------------------------------------------------------------------
// Kernel 3: bf16-split MFMA cosine GEMM + fused exp/z/top-3 SCREEN.
// Grid (NPC, 16). Block 256 = 4 waves. Block tile: 128 sess-rows x 128 pool.
// A (sess) frags stationary in registers (full K=256). B staged to LDS via
// global_load_lds from the pre-swizzled pool2 image.
// MFMA 16x16x32 bf16. C layout: col=lane&15, row=quad*4+reg (verified m89).
// Screened values have |err| <= ~3e-6 — used ONLY for candidate selection.
// ---------------------------------------------------------------------------
__launch_bounds__(256, 2)
__global__ void gemm_topk_kernel(const char* __restrict__ sess2,
                                 const char* __restrict__ pool2,
                                 float* __restrict__ partials) {
    __shared__ char lds[TILE_BYTES];

    const int tid = threadIdx.x;
    const int w   = tid >> 6;
    const int L   = tid & 63;
    const int q   = L >> 4;
    const int l15 = L & 15;
    const int l7  = L & 7;
    const int pc  = blockIdx.x;
    const int mt  = blockIdx.y;
    const int mrow_base = mt * 128 + w * 32;

    short8 afrag[2][8];
    #pragma unroll
    for (int i = 0; i < 2; ++i)
        #pragma unroll
        for (int ks = 0; ks < 8; ++ks)
            afrag[i][ks] = *(const short8*)(sess2 +
                (size_t)(mrow_base + i * 16 + l15) * 512 + (ks * 4 + q) * 16);

    float z[2][4];
    float tv[2][4][3];
    int   ti[2][4][3];
    #pragma unroll
    for (int i = 0; i < 2; ++i)
        #pragma unroll
        for (int r = 0; r < 4; ++r) {
            z[i][r] = 0.f;
            tv[i][r][0] = tv[i][r][1] = tv[i][r][2] = -1e30f;
            ti[i][r][0] = ti[i][r][1] = ti[i][r][2] = -1;
        }

    for (int T = pc; T < NT; T += NPC) {
        __syncthreads();
        const char* tb = pool2 + (size_t)T * TILE_BYTES;
        #pragma unroll
        for (int ii = 0; ii < 16; ++ii) {
            int idx = w * 16 + ii;
            async16(tb + idx * 1024 + L * 16, lds + idx * 1024);
        }
        __syncthreads();

        f32x4 acc[2][8];
        #pragma unroll
        for (int i = 0; i < 2; ++i)
            #pragma unroll
            for (int s = 0; s < 8; ++s)
                acc[i][s] = (f32x4){0.f, 0.f, 0.f, 0.f};

        #pragma unroll
        for (int ks = 0; ks < 8; ++ks) {
            const int sl = ((ks * 4 + q) ^ l7) * 16;
            short8 b[8];
            #pragma unroll
            for (int s = 0; s < 8; ++s)
                b[s] = *(const short8*)(lds + (s * 16 + l15) * 512 + sl);
            #pragma unroll
            for (int i = 0; i < 2; ++i)
                #pragma unroll
                for (int s = 0; s < 8; ++s)
                    acc[i][s] = __builtin_amdgcn_mfma_f32_16x16x32_bf16(
                        afrag[i][ks], b[s], acc[i][s], 0, 0, 0);
        }

        const int colbase = T * 128 + l15;
        #pragma unroll
        for (int s = 0; s < 8; ++s) {
            const int col = colbase + s * 16;
            const bool valid = col < P_ROWS;
            #pragma unroll
            for (int i = 0; i < 2; ++i)
                #pragma unroll
                for (int r = 0; r < 4; ++r) {
                    float v  = acc[i][s][r];
                    float e  = valid ? __expf(v) : 0.f;
                    float sv = valid ? v : -1e30f;
                    z[i][r] += e;
                    if (sv > tv[i][r][0]) {
                        tv[i][r][2] = tv[i][r][1]; ti[i][r][2] = ti[i][r][1];
                        tv[i][r][1] = tv[i][r][0]; ti[i][r][1] = ti[i][r][0];
                        tv[i][r][0] = sv;          ti[i][r][0] = col;
                    } else if (sv > tv[i][r][1]) {
                        tv[i][r][2] = tv[i][r][1]; ti[i][r][2] = ti[i][r][1];
                        tv[i][r][1] = sv;          ti[i][r][1] = col;
                    } else if (sv > tv[i][r][2]) {
                        tv[i][r][2] = sv;          ti[i][r][2] = col;
                    }
                }
        }
    }

    #pragma unroll
    for (int i = 0; i < 2; ++i)
        #pragma unroll
        for (int r = 0; r < 4; ++r) {
            float zz = z[i][r];
            float v0 = tv[i][r][0], v1 = tv[i][r][1], v2 = tv[i][r][2];
            int   i0 = ti[i][r][0], i1 = ti[i][r][1], i2 = ti[i][r][2];
            #pragma unroll
            for (int m = 1; m < 16; m <<= 1) {
                zz += __shfl_xor(zz, m);
                float pv0 = __shfl_xor(v0, m); int pi0 = __shfl_xor(i0, m);
                float pv1 = __shfl_xor(v1, m); int pi1 = __shfl_xor(i1, m);
                float pv2 = __shfl_xor(v2, m); int pi2 = __shfl_xor(i2, m);
                ins3(pv0, pi0, v0, i0, v1, i1, v2, i2);
                ins3(pv1, pi1, v0, i0, v1, i1, v2, i2);
                ins3(pv2, pi2, v0, i0, v1, i1, v2, i2);
            }
            if (l15 == 0) {
                int row = mt * 128 + w * 32 + i * 16 + q * 4 + r;
                float* o = partials + ((size_t)row * NPC + pc) * 8;
                o[0] = zz;
                o[1] = v0; o[2] = __int_as_float(i0);
                o[3] = v1; o[4] = __int_as_float(i1);
                o[5] = v2; o[6] = __int_as_float(i2);
                o[7] = 0.f;
            }
        }
}

// ---------------------------------------------------------------------------
// Kernel 4: per row — fp64 rescore of all 96 screened candidates, exact top-3
// (index tie-break), weights from fp64 values + screened z, gather, write.
// One block (256 thr = 4 waves) per row.
// ---------------------------------------------------------------------------
__launch_bounds__(256)
__global__ void finalize_kernel(const float* __restrict__ sess,
                                const float* __restrict__ pool,
                                const float* __restrict__ partials,
                                float* __restrict__ out_neighbor,
                                float* __restrict__ out_costopk,
                                float* __restrict__ out_sesstopk) {
    __shared__ int    cand_i[NCAND];
    __shared__ double cand_v[NCAND];
    __shared__ float  s_w[3];
    __shared__ int    s_i[3];

    const int row = blockIdx.x;
    const int tid = threadIdx.x;
    const int w   = tid >> 6;
    const int L   = tid & 63;

    // stage candidate indices (96 = 32 chunks x 3)
    if (tid < NCAND) {
        int c = tid / 3, k = tid - 3 * c;
        const float* q = partials + ((size_t)row * NPC + c) * 8;
        cand_i[tid] = __float_as_int(q[2 + 2 * k]);
    }

    // sess row (regs) + fp64 norm^2 incl eps, computed per wave
    const float2 sa = ((const float2*)(sess + (size_t)row * D_DIM))[L];
    double na = (double)sa.x * sa.x + (double)sa.y * sa.y;
    #pragma unroll
    for (int o = 32; o > 0; o >>= 1) na += __shfl_xor(na, o);
    na += (double)D_DIM * 1e-6;
    __syncthreads();

    // fp64 rescore: wave w handles candidates w, w+4, ...
    for (int j = w; j < NCAND; j += 4) {
        const float2 pb = ((const float2*)(pool + (size_t)cand_i[j] * D_DIM))[L];
        double dot = (double)sa.x * pb.x + (double)sa.y * pb.y;
        double nb  = (double)pb.x * pb.x + (double)pb.y * pb.y;
        #pragma unroll
        for (int o = 32; o > 0; o >>= 1) {
            dot += __shfl_xor(dot, o);
            nb  += __shfl_xor(nb,  o);
        }
        if (L == 0)
            cand_v[j] = dot / sqrt(na * (nb + (double)D_DIM * 1e-6));
    }
    __syncthreads();

    if (w == 0) {
        // exact top-3 over 96 candidates (wave 0)
        double v0 = cand_v[L], v1 = -1e300, v2 = -1e300;
        int    i0 = cand_i[L], i1 = 0x7fffffff, i2 = 0x7fffffff;
        if (L < NCAND - 64)
            ins3d(cand_v[64 + L], cand_i[64 + L], v0, i0, v1, i1, v2, i2);
        #pragma unroll
        for (int m = 1; m < 64; m <<= 1) {
            double pv0 = __shfl_xor(v0, m); int pi0 = __shfl_xor(i0, m);
            double pv1 = __shfl_xor(v1, m); int pi1 = __shfl_xor(i1, m);
            double pv2 = __shfl_xor(v2, m); int pi2 = __shfl_xor(i2, m);
            ins3d(pv0, pi0, v0, i0, v1, i1, v2, i2);
            ins3d(pv1, pi1, v0, i0, v1, i1, v2, i2);
            ins3d(pv2, pi2, v0, i0, v1, i1, v2, i2);
        }
        // z = sum of 32 chunk partials
        double z = (L < NPC) ? (double)partials[((size_t)row * NPC + L) * 8] : 0.0;
        #pragma unroll
        for (int o = 32; o > 0; o >>= 1) z += __shfl_xor(z, o);
        if (L == 0) {
            double c0 = exp(v0) / z, c1 = exp(v1) / z, c2 = exp(v2) / z;
            double e1 = exp(c1 - c0), e2 = exp(c2 - c0);
            double inv = 1.0 / (1.0 + e1 + e2);
            s_w[0] = (float)inv;
            s_w[1] = (float)(e1 * inv);
            s_w[2] = (float)(e2 * inv);
            s_i[0] = i0; s_i[1] = i1; s_i[2] = i2;
        }
    }
    __syncthreads();

    if (tid < D_DIM) {
        float g0 = pool[(size_t)s_i[0] * D_DIM + tid];
        float g1 = pool[(size_t)s_i[1] * D_DIM + tid];
        float g2 = pool[(size_t)s_i[2] * D_DIM + tid];
        out_sesstopk[((size_t)row * 3 + 0) * D_DIM + tid] = g0;
        out_sesstopk[((size_t)row * 3 + 1) * D_DIM + tid] = g1;
        out_sesstopk[((size_t)row * 3 + 2) * D_DIM + tid] = g2;
        out_neighbor[(size_t)row * D_DIM + tid] =
            s_w[0] * g0 + s_w[1] * g1 + s_w[2] * g2;
        if (tid < 3) out_costopk[row * 3 + tid] = s_w[tid];
    }
}

// ---------------------------------------------------------------------------
extern "C" void kernel_launch(void* const* d_in, const int* in_sizes, int n_in,
                              void* d_out, int out_size, void* d_ws, size_t ws_size,
                              hipStream_t stream) {
    const float* sess = (const float*)d_in[0];   // [2048,128]
    const float* pool = (const float*)d_in[1];   // [100000,128]
    float* out = (float*)d_out;
    float* out_neighbor = out;
    float* out_costopk  = out + (size_t)B_ROWS * D_DIM;
    float* out_sesstopk = out_costopk + (size_t)B_ROWS * 3;

    // workspace: inv_pool | inv_sess | partials (2MB) | sess2 (1MB) | pool2 (50MB)
    float* inv_pool = (float*)d_ws;
    float* inv_sess = inv_pool + P_ROWS;
    float* partials = inv_sess + B_ROWS;
    char*  sess2    = (char*)(partials + (size_t)B_ROWS * NPC * 8);
    char*  pool2    = sess2 + (size_t)B_ROWS * 512;

    norms_kernel<<<(P_ROWS + B_ROWS + 3) / 4, 256, 0, stream>>>(
        sess, pool, inv_sess, inv_pool);

    pack_sess_kernel<<<(B_ROWS * 16) / 256, 256, 0, stream>>>(
        sess, inv_sess, sess2);

    pack_pool_kernel<<<NT, 256, 0, stream>>>(
        pool, inv_pool, pool2);

    dim3 g3(NPC, B_ROWS / 128);
    gemm_topk_kernel<<<g3, 256, 0, stream>>>(sess2, pool2, partials);

    finalize_kernel<<<B_ROWS, 256, 0, stream>>>(
        sess, pool, partials, out_neighbor, out_costopk, out_sesstopk);
}

// Round 4
// 316.130 us; speedup vs baseline: 3.5801x; 1.4190x over previous
//
#include <hip/hip_runtime.h>
#include <math.h>

#define B_ROWS 2048
#define P_ROWS 100000
#define D_DIM  128
#define NPC    32                 // pool chunks (grid.x of gemm)
#define NT     782                // ceil(100000/128) pool tiles
#define TILE_BYTES 65536          // 128 cols x 256 bf16 (512 B/row)
#define NCAND  (NPC * 3)          // 96 screened candidates per row

typedef short short8 __attribute__((ext_vector_type(8)));
typedef float f32x4  __attribute__((ext_vector_type(4)));

// ---------------------------------------------------------------------------
// bf16 helpers (RNE)
// ---------------------------------------------------------------------------
__device__ __forceinline__ unsigned short f2bf(float f) {
    unsigned u = __float_as_uint(f);
    u += 0x7fffu + ((u >> 16) & 1u);
    return (unsigned short)(u >> 16);
}
__device__ __forceinline__ float bf2f(unsigned short h) {
    return __uint_as_float(((unsigned)h) << 16);
}

// ---------------------------------------------------------------------------
// Kernel 1: pack sess -> sess2[m][slot 0..31][16B], row-major, no swizzle.
// Norm fused: inv = 1/sqrt(sum(x^2) + 128e-6) computed in-block via LDS.
// Grid: 16 blocks x 256 thr; block handles 128 rows.
// ---------------------------------------------------------------------------
__global__ void pack_sess_kernel(const float* __restrict__ sess,
                                 char* __restrict__ sess2) {
    __shared__ float red[128][17];
    __shared__ float s_inv[128];
    const int tid  = threadIdx.x;
    const int base = blockIdx.x * 128;

    float4 d[8][2];
    #pragma unroll
    for (int it = 0; it < 8; ++it) {
        int item = it * 256 + tid;
        int c = item >> 4, g = item & 15;
        const float4* src = (const float4*)(sess + (size_t)(base + c) * D_DIM + g * 8);
        d[it][0] = src[0];
        d[it][1] = src[1];
        float4 a = d[it][0], b = d[it][1];
        red[c][g] = a.x*a.x + a.y*a.y + a.z*a.z + a.w*a.w
                  + b.x*b.x + b.y*b.y + b.z*b.z + b.w*b.w;
    }
    __syncthreads();
    if (tid < 128) {
        float s = 0.f;
        #pragma unroll
        for (int j = 0; j < 16; ++j) s += red[tid][j];
        s_inv[tid] = 1.0f / sqrtf(s + (float)D_DIM * 1e-6f);
    }
    __syncthreads();
    #pragma unroll
    for (int it = 0; it < 8; ++it) {
        int item = it * 256 + tid;
        int c = item >> 4, g = item & 15;
        float inv = s_inv[c];
        const float* f = (const float*)&d[it][0];
        short8 hv, lv;
        #pragma unroll
        for (int j = 0; j < 8; ++j) {
            float w = f[j] * inv;
            unsigned short h = f2bf(w);
            hv[j] = (short)h;
            lv[j] = (short)f2bf(w - bf2f(h));
        }
        char* o = sess2 + (size_t)(base + c) * 512;
        *(short8*)(o + g * 16)        = hv;
        *(short8*)(o + (16 + g) * 16) = lv;
    }
}

// ---------------------------------------------------------------------------
// Kernel 2: pack pool -> pool2[T][c][slot][16B], XOR-swizzled (slot stored at
// sg ^ (c&7)), norms fused, OOB rows -> zeros. Grid: NT blocks x 256 thr.
// ---------------------------------------------------------------------------
__global__ void pack_pool_kernel(const float* __restrict__ pool,
                                 char* __restrict__ pool2) {
    __shared__ float red[128][17];
    __shared__ float s_inv[128];
    const int tid = threadIdx.x;
    const int T   = blockIdx.x;

    float4 d[8][2];
    #pragma unroll
    for (int it = 0; it < 8; ++it) {
        int item = it * 256 + tid;
        int c = item >> 4, g = item & 15;
        int n = T * 128 + c;
        float4 a = make_float4(0.f,0.f,0.f,0.f), b = a;
        if (n < P_ROWS) {
            const float4* src = (const float4*)(pool + (size_t)n * D_DIM + g * 8);
            a = src[0]; b = src[1];
        }
        d[it][0] = a; d[it][1] = b;
        red[c][g] = a.x*a.x + a.y*a.y + a.z*a.z + a.w*a.w
                  + b.x*b.x + b.y*b.y + b.z*b.z + b.w*b.w;
    }
    __syncthreads();
    if (tid < 128) {
        float s = 0.f;
        #pragma unroll
        for (int j = 0; j < 16; ++j) s += red[tid][j];
        s_inv[tid] = 1.0f / sqrtf(s + (float)D_DIM * 1e-6f);
    }
    __syncthreads();
    #pragma unroll
    for (int it = 0; it < 8; ++it) {
        int item = it * 256 + tid;
        int c = item >> 4, g = item & 15;
        float inv = s_inv[c];
        const float* f = (const float*)&d[it][0];
        short8 hv, lv;
        #pragma unroll
        for (int j = 0; j < 8; ++j) {
            float w = f[j] * inv;
            unsigned short h = f2bf(w);
            hv[j] = (short)h;
            lv[j] = (short)f2bf(w - bf2f(h));
        }
        char* o = pool2 + (size_t)T * TILE_BYTES + c * 512;
        int x = c & 7;
        *(short8*)(o + (g ^ x) * 16)        = hv;
        *(short8*)(o + ((16 + g) ^ x) * 16) = lv;
    }
}

// branchless insert of key k into sorted-descending triple (t0 >= t1 >= t2)
__device__ __forceinline__ void kins(unsigned k, unsigned& t0, unsigned& t1,
                                     unsigned& t2) {
    unsigned m0 = min(t0, k); t0 = max(t0, k);
    unsigned m1 = min(t1, m0); t1 = max(t1, m0);
    t2 = max(t2, m1);
}

// fp64 top-3 insert with index tie-break (lower index wins)
__device__ __forceinline__ void ins3d(double v, int c,
                                      double& v0, int& i0,
                                      double& v1, int& i1,
                                      double& v2, int& i2) {
    bool b0 = (v > v0) || (v == v0 && c < i0);
    bool b1 = (v > v1) || (v == v1 && c < i1);
    bool b2 = (v > v2) || (v == v2 && c < i2);
    if (b0)      { v2 = v1; i2 = i1; v1 = v0; i1 = i0; v0 = v; i0 = c; }
    else if (b1) { v2 = v1; i2 = i1; v1 = v;  i1 = c; }
    else if (b2) { v2 = v;  i2 = c; }
}

__device__ __forceinline__ void async16(const char* g, char* l) {
    __builtin_amdgcn_global_load_lds(
        (const __attribute__((address_space(1))) unsigned int*)g,
        (__attribute__((address_space(3))) unsigned int*)l,
        16, 0, 0);
}

// ---------------------------------------------------------------------------
// Kernel 3: bf16-split MFMA cosine GEMM + fused exp/z/top-3 SCREEN.
// Grid (NPC, 16). Block 256 = 4 waves; tile 128 rows x 128 cols; wave: 32x128.
// A stationary in regs (full K=256); B via global_load_lds from pool2.
// Col loop split in halves (acc 32 regs live) to stay spill-free.
// Top-3 state: u32 keys = quant14(v)<<17 | (131071-col)  (branchless minmax).
// Invalid cols (96, chunk 13 only) contribute exp(0)=1 to z -> fixed in k4.
// ---------------------------------------------------------------------------
__launch_bounds__(256, 2)
__global__ void gemm_topk_kernel(const char* __restrict__ sess2,
                                 const char* __restrict__ pool2,
                                 uint4* __restrict__ partials) {
    __shared__ char lds[TILE_BYTES];

    const int tid = threadIdx.x;
    const int w   = tid >> 6;
    const int L   = tid & 63;
    const int q   = L >> 4;
    const int l15 = L & 15;
    const int l7  = L & 7;
    const int pc  = blockIdx.x;
    const int mt  = blockIdx.y;
    const int mrow_base = mt * 128 + w * 32;

    short8 afrag[2][8];
    #pragma unroll
    for (int i = 0; i < 2; ++i)
        #pragma unroll
        for (int ks = 0; ks < 8; ++ks)
            afrag[i][ks] = *(const short8*)(sess2 +
                (size_t)(mrow_base + i * 16 + l15) * 512 + (ks * 4 + q) * 16);

    float    z[2][4];
    unsigned key[2][4][3];
    #pragma unroll
    for (int i = 0; i < 2; ++i)
        #pragma unroll
        for (int r = 0; r < 4; ++r) {
            z[i][r] = 0.f;
            key[i][r][0] = key[i][r][1] = key[i][r][2] = 0u;
        }

    for (int T = pc; T < NT; T += NPC) {
        __syncthreads();
        const char* tb = pool2 + (size_t)T * TILE_BYTES;
        #pragma unroll
        for (int ii = 0; ii < 16; ++ii) {
            int idx = w * 16 + ii;
            async16(tb + idx * 1024 + L * 16, lds + idx * 1024);
        }
        __syncthreads();

        const unsigned kbase = 131071u - (unsigned)(T * 128) - (unsigned)l15;

        #pragma unroll
        for (int h = 0; h < 2; ++h) {
            f32x4 acc[2][4];
            #pragma unroll
            for (int i = 0; i < 2; ++i)
                #pragma unroll
                for (int js = 0; js < 4; ++js)
                    acc[i][js] = (f32x4){0.f, 0.f, 0.f, 0.f};

            #pragma unroll
            for (int ks = 0; ks < 8; ++ks) {
                const int sl = ((ks * 4 + q) ^ l7) * 16;
                short8 b[4];
                #pragma unroll
                for (int js = 0; js < 4; ++js)
                    b[js] = *(const short8*)(lds +
                        ((h * 4 + js) * 16 + l15) * 512 + sl);
                #pragma unroll
                for (int i = 0; i < 2; ++i)
                    #pragma unroll
                    for (int js = 0; js < 4; ++js)
                        acc[i][js] = __builtin_amdgcn_mfma_f32_16x16x32_bf16(
                            afrag[i][ks], b[js], acc[i][js], 0, 0, 0);
            }

            #pragma unroll
            for (int js = 0; js < 4; ++js) {
                const unsigned kb = kbase - (unsigned)((h * 4 + js) * 16);
                #pragma unroll
                for (int i = 0; i < 2; ++i)
                    #pragma unroll
                    for (int r = 0; r < 4; ++r) {
                        float v = acc[i][js][r];
                        z[i][r] += __expf(v);
                        unsigned ki = (unsigned)fmaf(v, 16384.f, 16384.f);
                        ki = min(ki, 32767u);
                        unsigned kk = (ki << 17) | kb;
                        kins(kk, key[i][r][0], key[i][r][1], key[i][r][2]);
                    }
            }
        }
    }

    // butterfly merge across the 16 lanes holding each row
    #pragma unroll
    for (int i = 0; i < 2; ++i)
        #pragma unroll
        for (int r = 0; r < 4; ++r) {
            float zz = z[i][r];
            unsigned t0 = key[i][r][0], t1 = key[i][r][1], t2 = key[i][r][2];
            #pragma unroll
            for (int m = 1; m < 16; m <<= 1) {
                zz += __shfl_xor(zz, m);
                unsigned r0 = __shfl_xor(t0, m);
                unsigned r1 = __shfl_xor(t1, m);
                unsigned r2 = __shfl_xor(t2, m);
                kins(r0, t0, t1, t2);
                kins(r1, t0, t1, t2);
                kins(r2, t0, t1, t2);
            }
            if (l15 == 0) {
                int row = mrow_base + i * 16 + q * 4 + r;
                partials[(size_t)row * NPC + pc] =
                    make_uint4(__float_as_uint(zz), t0, t1, t2);
            }
        }
}

// ---------------------------------------------------------------------------
// Kernel 4: per row — fp64 rescore of 96 screened candidates, exact top-3,
// double softmax (z from screen, minus 96 spurious exp(0)), gather, write.
// ---------------------------------------------------------------------------
__launch_bounds__(256)
__global__ void finalize_kernel(const float* __restrict__ sess,
                                const float* __restrict__ pool,
                                const uint4* __restrict__ partials,
                                float* __restrict__ out_neighbor,
                                float* __restrict__ out_costopk,
                                float* __restrict__ out_sesstopk) {
    __shared__ int    cand_i[NCAND];
    __shared__ double cand_v[NCAND];
    __shared__ float  s_w[3];
    __shared__ int    s_i[3];

    const int row = blockIdx.x;
    const int tid = threadIdx.x;
    const int w   = tid >> 6;
    const int L   = tid & 63;

    if (tid < NCAND) {
        int c = tid / 3, k = tid - 3 * c;
        unsigned kk = ((const unsigned*)&partials[(size_t)row * NPC + c])[1 + k];
        cand_i[tid] = 131071 - (int)(kk & 0x1FFFFu);   // >= P_ROWS if unfilled/invalid
    }

    const float2 sa = ((const float2*)(sess + (size_t)row * D_DIM))[L];
    double na = (double)sa.x * sa.x + (double)sa.y * sa.y;
    #pragma unroll
    for (int o = 32; o > 0; o >>= 1) na += __shfl_xor(na, o);
    na += (double)D_DIM * 1e-6;
    __syncthreads();

    for (int j = w; j < NCAND; j += 4) {
        int idx = cand_i[j];
        bool ok = idx < P_ROWS;
        float2 pb = make_float2(0.f, 0.f);
        if (ok) pb = ((const float2*)(pool + (size_t)idx * D_DIM))[L];
        double dot = (double)sa.x * pb.x + (double)sa.y * pb.y;
        double nb  = (double)pb.x * pb.x + (double)pb.y * pb.y;
        #pragma unroll
        for (int o = 32; o > 0; o >>= 1) {
            dot += __shfl_xor(dot, o);
            nb  += __shfl_xor(nb,  o);
        }
        if (L == 0)
            cand_v[j] = ok ? dot / sqrt(na * (nb + (double)D_DIM * 1e-6))
                           : -1e300;
    }
    __syncthreads();

    if (w == 0) {
        double v0 = cand_v[L], v1 = -1e300, v2 = -1e300;
        int    i0 = cand_i[L], i1 = 0x7fffffff, i2 = 0x7fffffff;
        if (L < NCAND - 64)
            ins3d(cand_v[64 + L], cand_i[64 + L], v0, i0, v1, i1, v2, i2);
        #pragma unroll
        for (int m = 1; m < 64; m <<= 1) {
            double pv0 = __shfl_xor(v0, m); int pi0 = __shfl_xor(i0, m);
            double pv1 = __shfl_xor(v1, m); int pi1 = __shfl_xor(i1, m);
            double pv2 = __shfl_xor(v2, m); int pi2 = __shfl_xor(i2, m);
            ins3d(pv0, pi0, v0, i0, v1, i1, v2, i2);
            ins3d(pv1, pi1, v0, i0, v1, i1, v2, i2);
            ins3d(pv2, pi2, v0, i0, v1, i1, v2, i2);
        }
        double zd = (L < NPC)
            ? (double)__uint_as_float(partials[(size_t)row * NPC + L].x) : 0.0;
        #pragma unroll
        for (int o = 32; o > 0; o >>= 1) zd += __shfl_xor(zd, o);
        if (L == 0) {
            double zc = zd - 96.0;   // remove exp(0) from the 96 padded cols
            double c0 = exp(v0) / zc, c1 = exp(v1) / zc, c2 = exp(v2) / zc;
            double e1 = exp(c1 - c0), e2 = exp(c2 - c0);
            double inv = 1.0 / (1.0 + e1 + e2);
            s_w[0] = (float)inv;
            s_w[1] = (float)(e1 * inv);
            s_w[2] = (float)(e2 * inv);
            s_i[0] = i0; s_i[1] = i1; s_i[2] = i2;
        }
    }
    __syncthreads();

    if (tid < D_DIM) {
        float g0 = pool[(size_t)s_i[0] * D_DIM + tid];
        float g1 = pool[(size_t)s_i[1] * D_DIM + tid];
        float g2 = pool[(size_t)s_i[2] * D_DIM + tid];
        out_sesstopk[((size_t)row * 3 + 0) * D_DIM + tid] = g0;
        out_sesstopk[((size_t)row * 3 + 1) * D_DIM + tid] = g1;
        out_sesstopk[((size_t)row * 3 + 2) * D_DIM + tid] = g2;
        out_neighbor[(size_t)row * D_DIM + tid] =
            s_w[0] * g0 + s_w[1] * g1 + s_w[2] * g2;
        if (tid < 3) out_costopk[row * 3 + tid] = s_w[tid];
    }
}

// ---------------------------------------------------------------------------
extern "C" void kernel_launch(void* const* d_in, const int* in_sizes, int n_in,
                              void* d_out, int out_size, void* d_ws, size_t ws_size,
                              hipStream_t stream) {
    const float* sess = (const float*)d_in[0];   // [2048,128]
    const float* pool = (const float*)d_in[1];   // [100000,128]
    float* out = (float*)d_out;
    float* out_neighbor = out;
    float* out_costopk  = out + (size_t)B_ROWS * D_DIM;
    float* out_sesstopk = out_costopk + (size_t)B_ROWS * 3;

    // workspace: partials (1MB) | sess2 (1MB) | pool2 (50MB)
    uint4* partials = (uint4*)d_ws;
    char*  sess2    = (char*)d_ws + (size_t)B_ROWS * NPC * 16;
    char*  pool2    = sess2 + (size_t)B_ROWS * 512;

    pack_sess_kernel<<<B_ROWS / 128, 256, 0, stream>>>(sess, sess2);
    pack_pool_kernel<<<NT, 256, 0, stream>>>(pool, pool2);

    dim3 g3(NPC, B_ROWS / 128);
    gemm_topk_kernel<<<g3, 256, 0, stream>>>(sess2, pool2, partials);

    finalize_kernel<<<B_ROWS, 256, 0, stream>>>(
        sess, pool, partials, out_neighbor, out_costopk, out_sesstopk);
}